// Round 11
// baseline (142.985 us; speedup 1.0000x reference)
//
#include <hip/hip_runtime.h>
#include <hip/hip_bf16.h>

// Two pairwise MLPs (ChG, DG) over 1024x1024 pairs, then A_chg @ A_gd, sigmoid.
// Outputs concat: [0:1M) sigmoid(A_chd), [1M:2M) A_chg, [2M:3M) A_gd (fp32).
//
// R11: R9's pipeline collapsed to TWO dispatches. (R10's single cooperative
// dispatch silently failed to launch -- all outputs zero -- likely
// CooperativeLaunchTooLarge; abandoned.) prep is inlined into branch_kernel:
// each block recomputes its own HL tile (20K MACs), HR fragment (160 FMA/lane)
// and W1 fragments (128 L1-cached loads/lane) directly from X/W0/W1, with the
// same fp32-accumulate + single RNE fp16 round as R9's prep -> bit-identical
// numerics (absmax must stay 0.03125). Kills the prep dispatch + hlhr global
// round-trip. gemm_sig stays a second dispatch (true grid dependency).

typedef _Float16 half8 __attribute__((ext_vector_type(8)));
typedef float floatx4 __attribute__((ext_vector_type(4)));
typedef float floatx2 __attribute__((ext_vector_type(2)));

union U4H8 { uint4 u; half8 h; };

#define LC 32
#define TSTRIDE 40   // lds_t row stride in halfwords: 2-way bank aliasing (free)

__global__ __launch_bounds__(256, 3) void branch_kernel(
    const float* __restrict__ Xch, const float* __restrict__ Xg,
    const float* __restrict__ Xd,
    const float* __restrict__ Wc0, const float* __restrict__ bc0,
    const float* __restrict__ W1c, const float* __restrict__ bc1,
    const float* __restrict__ Wcr, const float* __restrict__ bcr,
    const float* __restrict__ Wd0, const float* __restrict__ bd0,
    const float* __restrict__ W1d, const float* __restrict__ bd1,
    const float* __restrict__ Wdr, const float* __restrict__ bdr,
    float* __restrict__ d_out,
    _Float16* __restrict__ wsh)   // [0:1M) Achg f16 [ch][g], [1M:2M) AgdT f16 [d][g]
{
    __shared__ _Float16 hl_tile[LC * 128];       // 8 KB
    __shared__ _Float16 lds_t[64 * TSTRIDE];     // br1 transpose buffer (5 KB)

    const int bz = blockIdx.z;
    const float* Xl = bz ? Xg : Xch;   // left entity of the pair
    const float* Xr = bz ? Xd : Xg;    // right entity
    const float* W0 = bz ? Wd0 : Wc0;  // [10][128]
    const float* b0 = bz ? bd0 : bc0;
    const float* W1 = bz ? W1d : W1c;  // [128][64]
    const float* b1 = bz ? bd1 : bc1;
    const float* wr = bz ? Wdr : Wcr;
    const float brv = bz ? bdr[0] : bcr[0];
    float* outA = d_out + (bz ? 2097152 : 1048576);
    _Float16* outB = wsh + (bz ? 1048576 : 0);

    const int tid = threadIdx.x;
    const int lane = tid & 63, wave = tid >> 6;
    const int m = lane & 15, quad = lane >> 4;
    const int lbase = blockIdx.y * LC;
    const int rbase = blockIdx.x * 64;
    const int rm = rbase + wave * 16 + m;   // this lane's pair (column)

    // ---- inline prep 1: HL tile = Xl[lbase..+32] @ W0[:5] + b0 -> fp16 LDS
    // same fp32 accumulate order + single RNE round as R9's prep
#pragma unroll
    for (int i = 0; i < 16; ++i) {
        int o = tid + i * 256;           // [0, 4096)
        int row = o >> 7, col = o & 127;
        float s = b0[col];
#pragma unroll
        for (int j = 0; j < 5; ++j)
            s += Xl[(lbase + row) * 5 + j] * W0[j * 128 + col];
        hl_tile[o] = (_Float16)s;
    }

    // ---- inline prep 2: HR fragment (B-frag k-order: k = ks*32 + quad*8 + j8)
    float xr[5];
#pragma unroll
    for (int j = 0; j < 5; ++j) xr[j] = Xr[rm * 5 + j];
    half8 hr16[4];
#pragma unroll
    for (int ks = 0; ks < 4; ++ks) {
#pragma unroll
        for (int j8 = 0; j8 < 8; ++j8) {
            int k = ks * 32 + quad * 8 + j8;
            float s = 0.f;
#pragma unroll
            for (int j = 0; j < 5; ++j)
                s += xr[j] * W0[(5 + j) * 128 + k];
            hr16[ks][j8] = (_Float16)s;
        }
    }

    // ---- inline prep 3: W1^T A-fragments
    // w1f[mt][ks][j] = f16( W1[ks*32 + quad*8 + j][mt*16 + m] )
    half8 w1f[4][4];
#pragma unroll
    for (int mt = 0; mt < 4; ++mt)
#pragma unroll
        for (int ks = 0; ks < 4; ++ks)
#pragma unroll
            for (int j = 0; j < 8; ++j)
                w1f[mt][ks][j] = (_Float16)W1[(ks * 32 + quad * 8 + j) * 64 + mt * 16 + m];

    // per-lane n-slice constants: n = mt*16 + quad*4 + r
    floatx4 b1q[4];
    floatx2 wr2l[4], wr2h[4];
#pragma unroll
    for (int mt = 0; mt < 4; ++mt) {
        b1q[mt] = *(const floatx4*)(b1 + mt * 16 + quad * 4);
        floatx4 w4 = *(const floatx4*)(wr + mt * 16 + quad * 4);
        wr2l[mt] = __builtin_shufflevector(w4, w4, 0, 1);
        wr2h[mt] = __builtin_shufflevector(w4, w4, 2, 3);
    }

    const floatx2 z2 = (floatx2){0.f, 0.f};
    half8 hz;
#pragma unroll
    for (int j = 0; j < 8; ++j) hz[j] = (_Float16)0.f;

    __syncthreads();

#pragma unroll 2
    for (int li = 0; li < LC; ++li) {
        const _Float16* hlp = hl_tile + li * 128;

        // h = relu(hl16 + hr16) in packed fp16 -> B-fragments
        half8 bfr[4];
#pragma unroll
        for (int ks = 0; ks < 4; ++ks) {
            half8 hl8 = *(const half8*)(hlp + ks * 32 + quad * 8);
            bfr[ks] = __builtin_elementwise_max(hl8 + hr16[ks], hz);
        }

        floatx4 acc[4];
#pragma unroll
        for (int mt = 0; mt < 4; ++mt)
            acc[mt] = b1q[mt];   // b1 folded into the accumulator init
#pragma unroll
        for (int ks = 0; ks < 4; ++ks)
#pragma unroll
            for (int mt = 0; mt < 4; ++mt)
                acc[mt] = __builtin_amdgcn_mfma_f32_16x16x32_f16(w1f[mt][ks], bfr[ks], acc[mt], 0, 0, 0);

        // acc[mt][r] = h1[pair rm][n = mt*16+quad*4+r] + b1;  dot with Wr
        floatx2 y2 = z2;
#pragma unroll
        for (int mt = 0; mt < 4; ++mt) {
            floatx2 lo = __builtin_shufflevector(acc[mt], acc[mt], 0, 1);
            floatx2 hi = __builtin_shufflevector(acc[mt], acc[mt], 2, 3);
            y2 += __builtin_elementwise_max(lo, z2) * wr2l[mt];
            y2 += __builtin_elementwise_max(hi, z2) * wr2h[mt];
        }
        float y = y2[0] + y2[1];

        y += __shfl_xor(y, 16, 64);
        y += __shfl_xor(y, 32, 64);

        if (quad == 0) {
            float v = y + brv;
            float A = v > 0.f ? v : (expf(v) - 1.f);   // elu
            const int l = lbase + li;
            outA[l * 1024 + rm] = A;
            if (bz == 0)
                outB[l * 1024 + rm] = (_Float16)A;          // Achg [ch][g]
            else
                lds_t[(wave * 16 + m) * TSTRIDE + li] = (_Float16)A;   // stage
        }
    }

    if (bz == 1) {   // write AgdT [d][g] tiles, coalesced
        __syncthreads();
        int r = tid >> 2, seg = tid & 3;
        *(uint4*)(outB + (rbase + r) * 1024 + lbase + seg * 8) =
            *(const uint4*)(lds_t + r * TSTRIDE + seg * 8);
    }
}

// ---------------------------------------------------------------- final GEMM + sigmoid
// C[ch][d] = sum_g Achg[ch][g]*Agd[g][d]; fp16 MFMA, fp32 accum.
// 32x32 tiles, 1024 blocks (4/CU); dual accumulator for MFMA ILP.
__global__ __launch_bounds__(256) void gemm_sig(
    const _Float16* __restrict__ Ahf,   // [1024][1024] ch x g
    const _Float16* __restrict__ BThf,  // [1024][1024] d x g
    float* __restrict__ out0)
{
    __shared__ _Float16 At[32 * 72];   // +8 pad
    __shared__ _Float16 Bt[32 * 72];

    const int tid = threadIdx.x, lane = tid & 63, wave = tid >> 6;
    const int m = lane & 15, quad = lane >> 4;
    const int chbase = blockIdx.y * 32, dbase = blockIdx.x * 32;
    const int wrow = (wave >> 1) * 16, wcol = (wave & 1) * 16;

    floatx4 acc0 = (floatx4){0.f, 0.f, 0.f, 0.f};
    floatx4 acc1 = (floatx4){0.f, 0.f, 0.f, 0.f};

    const int row = tid >> 3, c4 = tid & 7;   // 32 rows x 8 uint4 = 256 threads
    uint4 ra = *(const uint4*)(Ahf + (chbase + row) * 1024 + c4 * 8);
    uint4 rb = *(const uint4*)(BThf + (dbase + row) * 1024 + c4 * 8);

    for (int kb = 0; kb < 1024; kb += 64) {
        *(uint4*)(At + row * 72 + c4 * 8) = ra;
        *(uint4*)(Bt + row * 72 + c4 * 8) = rb;
        __syncthreads();
        if (kb + 64 < 1024) {
            ra = *(const uint4*)(Ahf + (chbase + row) * 1024 + kb + 64 + c4 * 8);
            rb = *(const uint4*)(BThf + (dbase + row) * 1024 + kb + 64 + c4 * 8);
        }
        {
            half8 a0 = *(const half8*)(At + (wrow + m) * 72 + quad * 8);
            half8 b0 = *(const half8*)(Bt + (wcol + m) * 72 + quad * 8);
            half8 a1 = *(const half8*)(At + (wrow + m) * 72 + 32 + quad * 8);
            half8 b1 = *(const half8*)(Bt + (wcol + m) * 72 + 32 + quad * 8);
            acc0 = __builtin_amdgcn_mfma_f32_16x16x32_f16(a0, b0, acc0, 0, 0, 0);
            acc1 = __builtin_amdgcn_mfma_f32_16x16x32_f16(a1, b1, acc1, 0, 0, 0);
        }
        __syncthreads();
    }

    floatx4 acc = acc0 + acc1;
#pragma unroll
    for (int r = 0; r < 4; ++r) {
        int row_o = chbase + wrow + quad * 4 + r;
        int col_o = dbase + wcol + m;
        out0[row_o * 1024 + col_o] = 1.f / (1.f + expf(-acc[r]));
    }
}

// ---------------------------------------------------------------- launch
extern "C" void kernel_launch(void* const* d_in, const int* in_sizes, int n_in,
                              void* d_out, int out_size, void* d_ws, size_t ws_size,
                              hipStream_t stream) {
    const float* Xch = (const float*)d_in[0];
    const float* Xg  = (const float*)d_in[1];
    const float* Xd  = (const float*)d_in[2];
    const float* Wc0 = (const float*)d_in[3];
    const float* bc0 = (const float*)d_in[4];
    const float* Wc1 = (const float*)d_in[5];
    const float* bc1 = (const float*)d_in[6];
    const float* Wcr = (const float*)d_in[7];
    const float* bcr = (const float*)d_in[8];
    const float* Wd0 = (const float*)d_in[9];
    const float* bd0 = (const float*)d_in[10];
    const float* Wd1 = (const float*)d_in[11];
    const float* bd1 = (const float*)d_in[12];
    const float* Wdr = (const float*)d_in[13];
    const float* bdr = (const float*)d_in[14];

    float* out = (float*)d_out;
    _Float16* wsh = (_Float16*)d_ws;   // Achg f16 1M + AgdT f16 1M

    dim3 gb(16, 32, 2);   // (r-chunks of 64, l-chunks of 32, branch)
    branch_kernel<<<gb, 256, 0, stream>>>(Xch, Xg, Xd,
                                          Wc0, bc0, Wc1, bc1, Wcr, bcr,
                                          Wd0, bd0, Wd1, bd1, Wdr, bdr,
                                          out, wsh);

    dim3 gg(32, 32);
    gemm_sig<<<gg, 256, 0, stream>>>(wsh, wsh + 1048576, out);
}